// Round 7
// baseline (845.119 us; speedup 1.0000x reference)
//
#include <hip/hip_runtime.h>
#include <hip/hip_bf16.h>
#include <math.h>

typedef __attribute__((ext_vector_type(8))) short s16x8;
typedef __attribute__((ext_vector_type(4))) short s16x4;
typedef __attribute__((ext_vector_type(4))) float f32x4;
typedef __attribute__((ext_vector_type(8))) __bf16 bf16x8;

#define MFMA16(a, b, c) __builtin_amdgcn_mfma_f32_16x16x32_bf16( \
    __builtin_bit_cast(bf16x8, (a)), __builtin_bit_cast(bf16x8, (b)), (c), 0, 0, 0)

__device__ __forceinline__ short f2b(float f) {
    union { float f; unsigned u; } x; x.f = f;
    unsigned u = x.u;
    unsigned r = (u + 0x7FFFu + ((u >> 16) & 1u)) >> 16;
    return (short)r;
}
__device__ __forceinline__ float b2f(short b) {
    union { unsigned u; float f; } x;
    x.u = ((unsigned)(unsigned short)b) << 16;
    return x.f;
}

__device__ __forceinline__ void gload16(const void* g, void* l) {
    __builtin_amdgcn_global_load_lds(
        (const __attribute__((address_space(1))) unsigned int*)g,
        (__attribute__((address_space(3))) unsigned int*)l, 16, 0, 0);
}

// ---------------- fp32 -> bf16 convert ----------------
__global__ void k_f32_to_bf16(const float* __restrict__ in, short* __restrict__ out, long n) {
    long i = ((long)blockIdx.x * blockDim.x + threadIdx.x) * 4;
    long stride = (long)gridDim.x * blockDim.x * 4;
    for (; i < n; i += stride) {
        float4 v = *(const float4*)(in + i);
        s16x4 o = { f2b(v.x), f2b(v.y), f2b(v.z), f2b(v.w) };
        *(s16x4*)(out + i) = o;
    }
}

// ---------------- raw size with 0-padding (softmax weight; size in [1,2)) ----------------
__global__ void k_sizepad(const float* __restrict__ size, float* __restrict__ out,
                          int B, int T, int SP) {
    int i = blockIdx.x * blockDim.x + threadIdx.x;
    if (i >= B * SP) return;
    int b = i / SP, s = i % SP;
    out[i] = (s < T) ? size[b * T + s] : 0.f;
}

// ======== 256x256 8-wave GEMM, BK=32, 64KB LDS (2 blocks/CU), 1 barrier/K-tile ========
// Swizzle: 64B row of 4x16B slots; slot' = slot ^ ((r>>1)&3), applied on BOTH
// DMA source col and ds_read col (rule #21). Combined with odd/even row bank
// rotation -> 2-way aliasing (free).
__device__ __forceinline__ void stage256(const short* __restrict__ src, int ldk,
                                         int row0, int maxrow, int k0,
                                         short* lds, int tid) {
    #pragma unroll
    for (int j = 0; j < 2; ++j) {
        int ch = tid + j * 512;                 // 1024 chunks of 16B
        int r = ch >> 2, slot = ch & 3;
        int cby = (slot << 4) ^ (((r >> 1) & 3) << 4);
        int gr = row0 + r; gr = gr < maxrow ? gr : maxrow - 1;
        gload16((const char*)(src + (long)gr * ldk + k0) + cby,
                (char*)lds + ch * 16);
    }
}

__device__ __forceinline__ s16x8 frag32(const short* buf, int r, int lg) {
    int cby = (lg << 4) ^ (((r >> 1) & 3) << 4);
    return *(const s16x8*)((const char*)buf + r * 64 + cby);
}

template<bool ROUTE>
__global__ __launch_bounds__(512, 4) void k_gemm8(
    const short* __restrict__ A, const short* __restrict__ Bw,
    const float* __restrict__ bb0, const float* __restrict__ bb1, const float* __restrict__ bb2,
    short* __restrict__ o0, short* __restrict__ o1, short* __restrict__ o2,
    float* __restrict__ Cf, int M, int N, int K, int Ntiles, float alpha0) {

    __shared__ short AS[2][256 * 32];
    __shared__ short BS[2][256 * 32];

    int nwg = gridDim.x, orig = blockIdx.x;
    int qq = nwg >> 3, rr = nwg & 7;
    int xcd = orig & 7, pos = orig >> 3;
    int wg = (xcd < rr ? xcd * (qq + 1) : rr * (qq + 1) + (xcd - rr) * qq) + pos;
    int bx = wg % Ntiles, by = wg / Ntiles;
    int row0 = by * 256, col0 = bx * 256;

    int tid = threadIdx.x;
    int lane = tid & 63, wave = tid >> 6;
    int wm = wave >> 2, wn = wave & 3;          // 2 M-waves x 4 N-waves
    int lr = lane & 15, lg = lane >> 4;

    f32x4 acc[8][4];
    #pragma unroll
    for (int i = 0; i < 8; i++)
        #pragma unroll
        for (int j = 0; j < 4; j++)
            #pragma unroll
            for (int q = 0; q < 4; q++) acc[i][j][q] = 0.f;

    int nt = K >> 5;
    stage256(A,  K, row0, M, 0, AS[0], tid);
    stage256(Bw, K, col0, N, 0, BS[0], tid);

    for (int t = 0; t < nt; ++t) {
        int cur = t & 1;
        asm volatile("s_waitcnt vmcnt(0)" ::: "memory");   // own stages landed
        __builtin_amdgcn_s_barrier();                       // all stages visible, prev reads done
        if (t + 1 < nt) {                                   // prefetch next tile
            int k1 = (t + 1) << 5;
            stage256(A,  K, row0, M, k1, AS[cur ^ 1], tid);
            stage256(Bw, K, col0, N, k1, BS[cur ^ 1], tid);
        }
        const short* Ab2 = AS[cur];
        const short* Bb2 = BS[cur];
        s16x8 bf[4];
        #pragma unroll
        for (int nf = 0; nf < 4; ++nf)
            bf[nf] = frag32(Bb2, wn * 64 + nf * 16 + lr, lg);
        #pragma unroll
        for (int p = 0; p < 4; ++p) {
            s16x8 af[2];
            #pragma unroll
            for (int i = 0; i < 2; ++i)
                af[i] = frag32(Ab2, wm * 128 + (2 * p + i) * 16 + lr, lg);
            __builtin_amdgcn_s_setprio(1);
            #pragma unroll
            for (int i = 0; i < 2; ++i)
                #pragma unroll
                for (int nf = 0; nf < 4; ++nf)
                    acc[2 * p + i][nf] = MFMA16(af[i], bf[nf], acc[2 * p + i][nf]);
            __builtin_amdgcn_s_setprio(0);
        }
    }

    int wrow = row0 + wm * 128;
    #pragma unroll
    for (int mf = 0; mf < 8; ++mf) {
        int grow = wrow + mf * 16 + lg * 4;
        #pragma unroll
        for (int nf = 0; nf < 4; ++nf) {
            int gc = col0 + wn * 64 + nf * 16 + lr;
            if (gc >= N) continue;
            if (ROUTE) {
                int which = gc >> 10, lc = gc & 1023;
                float bias = (which == 0 ? bb0 : which == 1 ? bb1 : bb2)[lc];
                float alpha = (which == 0) ? alpha0 : 1.0f;
                short* op = (which == 0 ? o0 : which == 1 ? o1 : o2);
                #pragma unroll
                for (int q = 0; q < 4; ++q) {
                    int r2 = grow + q;
                    if (r2 < M) op[(long)r2 * 1024 + lc] = f2b((acc[mf][nf][q] + bias) * alpha);
                }
            } else {
                float bias = bb0[gc];
                #pragma unroll
                for (int q = 0; q < 4; ++q) {
                    int r2 = grow + q;
                    if (r2 < M) Cf[(long)r2 * N + gc] = acc[mf][nf][q] + bias;
                }
            }
        }
    }
}

// ---------------- 128^2 core for att partials ----------------
__device__ __forceinline__ void gemm_core(
    const short* __restrict__ Ab, const short* __restrict__ Bb,
    float* __restrict__ Cf, int M, int N, int K, int ldc, int row0, int col0) {
    __shared__ short As[128 * 64];
    __shared__ short Bs[128 * 64];
    int tid = threadIdx.x;
    int lane = tid & 63, wave = tid >> 6;
    int wr = wave >> 1, wc = wave & 1;
    int lr = lane & 15, lg = lane >> 4;
    f32x4 acc[4][4];
    #pragma unroll
    for (int i = 0; i < 4; i++)
        #pragma unroll
        for (int j = 0; j < 4; j++)
            #pragma unroll
            for (int q = 0; q < 4; q++) acc[i][j][q] = 0.f;

    for (int k0 = 0; k0 < K; k0 += 64) {
        __syncthreads();
        #pragma unroll
        for (int i = 0; i < 4; ++i) {
            int cw = i * 256 + wave * 64;
            int c = cw + lane;
            int r = c >> 3;
            int cs = (c & 7) * 8;
            int ra = row0 + r; ra = ra < M ? ra : M - 1;
            gload16(Ab + (long)ra * K + k0 + cs, &As[cw * 8]);
            int rb = col0 + r; rb = rb < N ? rb : N - 1;
            gload16(Bb + (long)rb * K + k0 + cs, &Bs[cw * 8]);
        }
        __syncthreads();
        #pragma unroll
        for (int ks = 0; ks < 2; ++ks) {
            s16x8 af[4], bfr[4];
            #pragma unroll
            for (int i = 0; i < 4; ++i)
                af[i] = *(const s16x8*)&As[(wr * 64 + i * 16 + lr) * 64 + ks * 32 + lg * 8];
            #pragma unroll
            for (int j = 0; j < 4; ++j)
                bfr[j] = *(const s16x8*)&Bs[(wc * 64 + j * 16 + lr) * 64 + ks * 32 + lg * 8];
            #pragma unroll
            for (int i = 0; i < 4; ++i)
                #pragma unroll
                for (int j = 0; j < 4; ++j)
                    acc[i][j] = MFMA16(af[i], bfr[j], acc[i][j]);
        }
    }
    #pragma unroll
    for (int i = 0; i < 4; i++) {
        int rbase = row0 + wr * 64 + i * 16 + lg * 4;
        #pragma unroll
        for (int j = 0; j < 4; j++) {
            int c = col0 + wc * 64 + j * 16 + lr;
            if (c >= N) continue;
            #pragma unroll
            for (int q = 0; q < 4; q++) {
                int r = rbase + q;
                if (r >= M) continue;
                Cf[(long)r * ldc + c] = acc[i][j][q];
            }
        }
    }
}

__global__ __launch_bounds__(256) void k_att(
    const short* __restrict__ q, const short* __restrict__ k,
    float* __restrict__ attp, int T, int E) {
    int z = blockIdx.z;
    gemm_core(q + (long)z * T * E, k + (long)z * T * E,
              attp + (long)z * T * T, T, T, E, T,
              blockIdx.y * 128, blockIdx.x * 128);
}

// ---------------- mean over heads of K ----------------
__global__ void k_mean_keys8(const short* __restrict__ Kb, float* __restrict__ out, int BT) {
    int i = blockIdx.x * blockDim.x + threadIdx.x;
    if (i >= BT * 8) return;
    int bt = i >> 3, d0 = (i & 7) * 8;
    const short* p = Kb + (long)bt * 1024 + d0;
    float s[8] = {0.f, 0.f, 0.f, 0.f, 0.f, 0.f, 0.f, 0.f};
    #pragma unroll
    for (int h = 0; h < 16; ++h) {
        s16x8 v = *(const s16x8*)(p + h * 64);
        #pragma unroll
        for (int j = 0; j < 8; ++j) s[j] += b2f(v[j]);
    }
    float4 o0 = {s[0] * 0.0625f, s[1] * 0.0625f, s[2] * 0.0625f, s[3] * 0.0625f};
    float4 o1 = {s[4] * 0.0625f, s[5] * 0.0625f, s[6] * 0.0625f, s[7] * 0.0625f};
    *(float4*)(out + (long)bt * 64 + d0) = o0;
    *(float4*)(out + (long)bt * 64 + d0 + 4) = o1;
}

// ---------------- reduce att_score partials over batch ----------------
// scale = ln2/256 compensates the log2e folded into q
__global__ void k_att_reduce(const float* __restrict__ part, float* __restrict__ out,
                             int n, int nb, long stride) {
    int i = blockIdx.x * blockDim.x + threadIdx.x;
    if (i >= n) return;
    float s = 0.f;
    for (int b = 0; b < nb; ++b) s += part[(long)b * stride + i];
    out[i] = s * 0.002707606174062286f;  // ln(2)/256
}

// ---------------- V transpose: v[B,T,H*64] -> vt[B*H][64][TP] ----------------
__global__ __launch_bounds__(256) void k_vtrans(const short* __restrict__ v, short* __restrict__ vt,
                                                int B, int T, int H, int TP) {
    int b = blockIdx.z, h = blockIdx.y, t0 = blockIdx.x * 64;
    __shared__ short Vs[64][68];
    int tid = threadIdx.x;
    for (int c = tid; c < 512; c += 256) {
        int r = c >> 3, m = c & 7;
        s16x8 val = {0,0,0,0,0,0,0,0};
        if (t0 + r < T) val = *(const s16x8*)(v + ((long)(b * T + t0 + r)) * (H * 64) + h * 64 + m * 8);
        *(s16x8*)&Vs[r][m * 8] = val;
    }
    __syncthreads();
    for (int c = tid; c < 512; c += 256) {
        int d = c >> 3, mw = c & 7;
        s16x8 o;
        #pragma unroll
        for (int j = 0; j < 8; j++) o[j] = Vs[mw * 8 + j][d];
        *(s16x8*)(vt + ((long)((b * H + h) * 64 + d)) * TP + t0 + mw * 8) = o;
    }
}

// ---------------- flash attention v4: size-weighted exp2 softmax, per-lane lsum ----------------
__global__ __launch_bounds__(256) void k_flash(
    const short* __restrict__ Q, const short* __restrict__ Kb, const short* __restrict__ VT,
    const float* __restrict__ szp, short* __restrict__ Ctx,
    int B, int T, int E, int H, int SP, int TP, int NTQ) {
    int nwg = gridDim.x;
    int cpx = nwg >> 3;
    int wg = (blockIdx.x & 7) * cpx + (blockIdx.x >> 3);
    int tq = wg % NTQ, h = (wg / NTQ) % H, b = wg / (NTQ * H);
    int t0 = tq * 128;

    __shared__ short Ks[64][68];
    __shared__ short Vt[64][68];
    __shared__ short Ps[4][32][68];
    __shared__ float Ls[64];
    int tid = threadIdx.x, wid = tid >> 6, lane = tid & 63;
    int lr = lane & 15, lg = lane >> 4;

    s16x8 aqf[2][2];
    #pragma unroll
    for (int i = 0; i < 2; ++i) {
        int t = t0 + wid * 32 + i * 16 + lr; t = t < T ? t : T - 1;
        #pragma unroll
        for (int ks = 0; ks < 2; ++ks)
            aqf[i][ks] = *(const s16x8*)(Q + ((long)b * T + t) * E + h * 64 + ks * 32 + lg * 8);
    }

    const short* kb  = Kb + (long)b * T * E + h * 64;
    const short* vtb = VT + ((long)(b * H + h)) * 64 * TP;

    int c0 = tid, c1 = tid + 256;
    int r0 = c0 >> 3, m0 = c0 & 7, r1 = c1 >> 3, m1 = c1 & 7;
    s16x8 kreg0, kreg1, vreg0, vreg1;
    float lreg = 0.f;

    {
        int s = r0; s = s < T ? s : T - 1;
        kreg0 = *(const s16x8*)(kb + (long)s * E + m0 * 8);
        s = r1; s = s < T ? s : T - 1;
        kreg1 = *(const s16x8*)(kb + (long)s * E + m1 * 8);
        vreg0 = *(const s16x8*)(vtb + (long)r0 * TP + 0 + m0 * 8);
        vreg1 = *(const s16x8*)(vtb + (long)r1 * TP + 0 + m1 * 8);
        if (tid < 64) lreg = szp[b * SP + 0 + tid];
    }

    float mreg[2][4], lsum[2][4];
    f32x4 o[2][4];
    #pragma unroll
    for (int i = 0; i < 2; i++)
        #pragma unroll
        for (int q = 0; q < 4; q++) { mreg[i][q] = -INFINITY; lsum[i][q] = 0.f; }
    #pragma unroll
    for (int i = 0; i < 2; i++)
        #pragma unroll
        for (int jd = 0; jd < 4; jd++)
            #pragma unroll
            for (int q = 0; q < 4; q++) o[i][jd][q] = 0.f;

    for (int s0 = 0; s0 < T; s0 += 64) {
        *(s16x8*)&Ks[r0][m0 * 8] = kreg0;
        *(s16x8*)&Ks[r1][m1 * 8] = kreg1;
        *(s16x8*)&Vt[r0][m0 * 8] = vreg0;
        *(s16x8*)&Vt[r1][m1 * 8] = vreg1;
        if (tid < 64) Ls[tid] = lreg;
        __syncthreads();

        if (s0 + 64 < T) {
            int sn = s0 + 64;
            int s = sn + r0; s = s < T ? s : T - 1;
            kreg0 = *(const s16x8*)(kb + (long)s * E + m0 * 8);
            s = sn + r1; s = s < T ? s : T - 1;
            kreg1 = *(const s16x8*)(kb + (long)s * E + m1 * 8);
            vreg0 = *(const s16x8*)(vtb + (long)r0 * TP + sn + m0 * 8);
            vreg1 = *(const s16x8*)(vtb + (long)r1 * TP + sn + m1 * 8);
            if (tid < 64) lreg = szp[b * SP + sn + tid];
        }

        float szv[4];
        #pragma unroll
        for (int j = 0; j < 4; j++) szv[j] = Ls[j * 16 + lr];

        s16x8 kf[2][4];
        #pragma unroll
        for (int ks = 0; ks < 2; ++ks)
            #pragma unroll
            for (int j = 0; j < 4; ++j)
                kf[ks][j] = *(const s16x8*)&Ks[j * 16 + lr][ks * 32 + lg * 8];

        #pragma unroll
        for (int i = 0; i < 2; ++i) {
            f32x4 sf[4];
            #pragma unroll
            for (int j = 0; j < 4; j++)
                #pragma unroll
                for (int q = 0; q < 4; q++) sf[j][q] = 0.f;
            __builtin_amdgcn_s_setprio(1);
            #pragma unroll
            for (int ks = 0; ks < 2; ++ks)
                #pragma unroll
                for (int j = 0; j < 4; j++) sf[j] = MFMA16(aqf[i][ks], kf[ks][j], sf[j]);
            __builtin_amdgcn_s_setprio(0);

            float tmax[4];
            #pragma unroll
            for (int q = 0; q < 4; q++)
                tmax[q] = fmaxf(fmaxf(sf[0][q], sf[1][q]), fmaxf(sf[2][q], sf[3][q]));
            int ok = 1;
            #pragma unroll
            for (int q = 0; q < 4; q++) ok &= (tmax[q] <= mreg[i][q] + 11.0f) ? 1 : 0;
            if (!__all(ok)) {
                #pragma unroll
                for (int q = 0; q < 4; q++) {
                    #pragma unroll
                    for (int msk = 1; msk < 16; msk <<= 1)
                        tmax[q] = fmaxf(tmax[q], __shfl_xor(tmax[q], msk));
                    float mn = fmaxf(mreg[i][q], tmax[q]);
                    float al = exp2f(mreg[i][q] - mn);
                    mreg[i][q] = mn;
                    lsum[i][q] *= al;
                    #pragma unroll
                    for (int jd = 0; jd < 4; jd++) o[i][jd][q] *= al;
                }
            }
            float rs[4] = {0.f, 0.f, 0.f, 0.f};
            #pragma unroll
            for (int j = 0; j < 4; j++) {
                float szj = szv[j];
                #pragma unroll
                for (int q = 0; q < 4; q++) {
                    float p = exp2f(sf[j][q] - mreg[i][q]) * szj;
                    sf[j][q] = p;
                    rs[q] += p;
                }
            }
            #pragma unroll
            for (int q = 0; q < 4; q++) lsum[i][q] += rs[q];

            #pragma unroll
            for (int j = 0; j < 4; j++)
                #pragma unroll
                for (int q = 0; q < 4; q++)
                    Ps[wid][i * 16 + lg * 4 + q][j * 16 + lr] = f2b(sf[j][q]);

            __builtin_amdgcn_s_setprio(1);
            #pragma unroll
            for (int ks = 0; ks < 2; ++ks) {
                s16x8 ap = *(const s16x8*)&Ps[wid][i * 16 + lr][ks * 32 + lg * 8];
                #pragma unroll
                for (int jd = 0; jd < 4; jd++) {
                    s16x8 bv = *(const s16x8*)&Vt[jd * 16 + lr][ks * 32 + lg * 8];
                    o[i][jd] = MFMA16(ap, bv, o[i][jd]);
                }
            }
            __builtin_amdgcn_s_setprio(0);
        }
        __syncthreads();
    }

    short* cb = Ctx + ((long)b * T + t0) * E + h * 64;
    #pragma unroll
    for (int i = 0; i < 2; i++)
        #pragma unroll
        for (int q = 0; q < 4; q++) {
            float s = lsum[i][q];
            s += __shfl_xor(s, 1); s += __shfl_xor(s, 2);
            s += __shfl_xor(s, 4); s += __shfl_xor(s, 8);
            int t = wid * 32 + i * 16 + lg * 4 + q;
            if (t0 + t >= T) continue;
            float inv = 1.f / s;
            #pragma unroll
            for (int jd = 0; jd < 4; jd++)
                cb[(long)t * E + jd * 16 + lr] = f2b(o[i][jd][q] * inv);
        }
}

extern "C" void kernel_launch(void* const* d_in, const int* in_sizes, int n_in,
                              void* d_out, int out_size, void* d_ws, size_t ws_size,
                              hipStream_t stream) {
    (void)in_sizes; (void)n_in; (void)out_size; (void)ws_size;
    const int B = 16, T = 577, E = 1024, H = 16;
    const int SP = 640, TP = 640;
    const float* hs   = (const float*)d_in[0];
    const float* size = (const float*)d_in[1];
    const float* wq   = (const float*)d_in[2];
    const float* bq   = (const float*)d_in[3];
    const float* wk   = (const float*)d_in[4];
    const float* bk   = (const float*)d_in[5];
    const float* wv   = (const float*)d_in[6];
    const float* bv   = (const float*)d_in[7];
    const float* wo   = (const float*)d_in[8];
    const float* bo   = (const float*)d_in[9];

    float* out_attn = (float*)d_out;                  // B*T*E
    float* out_mk   = out_attn + (long)B * T * E;     // B*T*D
    float* out_as   = out_mk + (long)B * T * 64;      // T*T

    long nBTE = (long)B * T * E;
    long nEE  = (long)E * E;
    char* ws = (char*)d_ws;
    short* hs_b  = (short*)ws; ws += nBTE * 2;
    short* wq_b  = (short*)ws; ws += nEE * 2;   // wq|wk|wv contiguous -> [3072][1024]
    short* wk_b  = (short*)ws; ws += nEE * 2;
    short* wv_b  = (short*)ws; ws += nEE * 2;
    short* wo_b  = (short*)ws; ws += nEE * 2;
    short* q_b   = (short*)ws; ws += nBTE * 2;
    short* k_b   = (short*)ws; ws += nBTE * 2;
    short* v_b   = (short*)ws; ws += nBTE * 2;
    short* ctx_b = (short*)ws; ws += nBTE * 2;
    float* szpad = (float*)ws; ws += (long)B * SP * 4;
    float* att_p = (float*)ws; ws += (long)B * T * T * 4;
    short* vt = (short*)att_p;   // aliases att_p, written after reduce consumed it

    k_f32_to_bf16<<<2048, 256, 0, stream>>>(hs, hs_b, nBTE);
    k_f32_to_bf16<<<1024, 256, 0, stream>>>(wq, wq_b, nEE);
    k_f32_to_bf16<<<1024, 256, 0, stream>>>(wk, wk_b, nEE);
    k_f32_to_bf16<<<1024, 256, 0, stream>>>(wv, wv_b, nEE);
    k_f32_to_bf16<<<1024, 256, 0, stream>>>(wo, wo_b, nEE);
    k_sizepad<<<(B * SP + 255) / 256, 256, 0, stream>>>(size, szpad, B, T, SP);

    int M = B * T;  // 9232
    // fused QKV; q carries 0.125*log2(e) for exp2-domain softmax (compensated in att_reduce)
    {
        int Mtiles = (M + 255) / 256, Ntiles = 3072 / 256;
        k_gemm8<true><<<Mtiles * Ntiles, 512, 0, stream>>>(
            hs_b, wq_b, bq, bk, bv, q_b, k_b, v_b, nullptr, M, 3072, E, Ntiles,
            0.18033688011112042f);  // 0.125 * log2(e)
    }

    dim3 g_att((T + 127) / 128, (T + 127) / 128, B);
    k_att<<<g_att, dim3(256), 0, stream>>>(q_b, k_b, att_p, T, E);
    k_att_reduce<<<((T * T) + 255) / 256, 256, 0, stream>>>(att_p, out_as, T * T, B, (long)T * T);

    dim3 g_vt((T + 63) / 64, H, B);
    k_vtrans<<<g_vt, dim3(256), 0, stream>>>(v_b, vt, B, T, H, TP);

    k_mean_keys8<<<((B * T * 8) + 255) / 256, 256, 0, stream>>>(k_b, out_mk, B * T);

    const int NTQ = (T + 127) / 128;
    int nfl = NTQ * H * B;
    k_flash<<<nfl, dim3(256), 0, stream>>>(q_b, k_b, vt, szpad, ctx_b, B, T, E, H, SP, TP, NTQ);

    {
        int Mtiles = (M + 255) / 256, Ntiles = 1024 / 256;
        k_gemm8<false><<<Mtiles * Ntiles, 512, 0, stream>>>(
            ctx_b, wo_b, bo, nullptr, nullptr, nullptr, nullptr, nullptr,
            out_attn, M, 1024, E, Ntiles, 1.0f);
    }
}

// Round 8
// 330.033 us; speedup vs baseline: 2.5607x; 2.5607x over previous
//
#include <hip/hip_runtime.h>
#include <hip/hip_bf16.h>
#include <math.h>

typedef __attribute__((ext_vector_type(8))) short s16x8;
typedef __attribute__((ext_vector_type(4))) short s16x4;
typedef __attribute__((ext_vector_type(4))) float f32x4;
typedef __attribute__((ext_vector_type(8))) __bf16 bf16x8;

#define MFMA16(a, b, c) __builtin_amdgcn_mfma_f32_16x16x32_bf16( \
    __builtin_bit_cast(bf16x8, (a)), __builtin_bit_cast(bf16x8, (b)), (c), 0, 0, 0)

__device__ __forceinline__ short f2b(float f) {
    union { float f; unsigned u; } x; x.f = f;
    unsigned u = x.u;
    unsigned r = (u + 0x7FFFu + ((u >> 16) & 1u)) >> 16;
    return (short)r;
}
__device__ __forceinline__ float b2f(short b) {
    union { unsigned u; float f; } x;
    x.u = ((unsigned)(unsigned short)b) << 16;
    return x.f;
}

__device__ __forceinline__ void gload16(const void* g, void* l) {
    __builtin_amdgcn_global_load_lds(
        (const __attribute__((address_space(1))) unsigned int*)g,
        (__attribute__((address_space(3))) unsigned int*)l, 16, 0, 0);
}

// ---------------- fp32 -> bf16 convert ----------------
__global__ void k_f32_to_bf16(const float* __restrict__ in, short* __restrict__ out, long n) {
    long i = ((long)blockIdx.x * blockDim.x + threadIdx.x) * 4;
    long stride = (long)gridDim.x * blockDim.x * 4;
    for (; i < n; i += stride) {
        float4 v = *(const float4*)(in + i);
        s16x4 o = { f2b(v.x), f2b(v.y), f2b(v.z), f2b(v.w) };
        *(s16x4*)(out + i) = o;
    }
}

// ---------------- raw size with 0-padding (softmax weight; size in [1,2)) ----------------
__global__ void k_sizepad(const float* __restrict__ size, float* __restrict__ out,
                          int B, int T, int SP) {
    int i = blockIdx.x * blockDim.x + threadIdx.x;
    if (i >= B * SP) return;
    int b = i / SP, s = i % SP;
    out[i] = (s < T) ? size[b * T + s] : 0.f;
}

// ======== 256x256 8-wave GEMM, BK=32, 64KB LDS (2 blocks/CU), 1 barrier/K-tile ========
// Swizzle: 64B row of 4x16B slots; slot' = slot ^ ((r>>1)&3), applied on BOTH
// DMA source col and ds_read col (rule #21). Validated on HW in round 7.
__device__ __forceinline__ void stage256(const short* __restrict__ src, int ldk,
                                         int row0, int maxrow, int k0,
                                         short* lds, int tid) {
    #pragma unroll
    for (int j = 0; j < 2; ++j) {
        int ch = tid + j * 512;                 // 1024 chunks of 16B
        int r = ch >> 2, slot = ch & 3;
        int cby = (slot << 4) ^ (((r >> 1) & 3) << 4);
        int gr = row0 + r; gr = gr < maxrow ? gr : maxrow - 1;
        gload16((const char*)(src + (long)gr * ldk + k0) + cby,
                (char*)lds + ch * 16);
    }
}

__device__ __forceinline__ s16x8 frag32(const short* buf, int r, int lg) {
    int cby = (lg << 4) ^ (((r >> 1) & 3) << 4);
    return *(const s16x8*)((const char*)buf + r * 64 + cby);
}

// NOTE: second launch_bounds arg behaves as min BLOCKS/CU (CUDA semantics) here:
// (512,4) capped VGPR at 64 -> acc spilled -> 1.47GB scratch writes (round 7).
// (512,2) => 128-VGPR cap, kernel fits (~104), LDS 64KB => 2 blocks/CU.
template<bool ROUTE>
__global__ __launch_bounds__(512, 2) void k_gemm8(
    const short* __restrict__ A, const short* __restrict__ Bw,
    const float* __restrict__ bb0, const float* __restrict__ bb1, const float* __restrict__ bb2,
    short* __restrict__ o0, short* __restrict__ o1, short* __restrict__ o2,
    float* __restrict__ Cf, int M, int N, int K, int Ntiles, float alpha0) {

    __shared__ short AS[2][256 * 32];
    __shared__ short BS[2][256 * 32];

    int nwg = gridDim.x, orig = blockIdx.x;
    int qq = nwg >> 3, rr = nwg & 7;
    int xcd = orig & 7, pos = orig >> 3;
    int wg = (xcd < rr ? xcd * (qq + 1) : rr * (qq + 1) + (xcd - rr) * qq) + pos;
    int bx = wg % Ntiles, by = wg / Ntiles;
    int row0 = by * 256, col0 = bx * 256;

    int tid = threadIdx.x;
    int lane = tid & 63, wave = tid >> 6;
    int wm = wave >> 2, wn = wave & 3;          // 2 M-waves x 4 N-waves
    int lr = lane & 15, lg = lane >> 4;

    f32x4 acc[8][4];
    #pragma unroll
    for (int i = 0; i < 8; i++)
        #pragma unroll
        for (int j = 0; j < 4; j++)
            #pragma unroll
            for (int q = 0; q < 4; q++) acc[i][j][q] = 0.f;

    int nt = K >> 5;
    stage256(A,  K, row0, M, 0, AS[0], tid);
    stage256(Bw, K, col0, N, 0, BS[0], tid);

    for (int t = 0; t < nt; ++t) {
        int cur = t & 1;
        asm volatile("s_waitcnt vmcnt(0)" ::: "memory");   // own stages landed
        __builtin_amdgcn_s_barrier();                       // all stages visible, prev reads done
        if (t + 1 < nt) {                                   // prefetch next tile
            int k1 = (t + 1) << 5;
            stage256(A,  K, row0, M, k1, AS[cur ^ 1], tid);
            stage256(Bw, K, col0, N, k1, BS[cur ^ 1], tid);
        }
        const short* Ab2 = AS[cur];
        const short* Bb2 = BS[cur];
        s16x8 bf[4];
        #pragma unroll
        for (int nf = 0; nf < 4; ++nf)
            bf[nf] = frag32(Bb2, wn * 64 + nf * 16 + lr, lg);
        #pragma unroll
        for (int p = 0; p < 4; ++p) {
            s16x8 af[2];
            #pragma unroll
            for (int i = 0; i < 2; ++i)
                af[i] = frag32(Ab2, wm * 128 + (2 * p + i) * 16 + lr, lg);
            __builtin_amdgcn_s_setprio(1);
            #pragma unroll
            for (int i = 0; i < 2; ++i)
                #pragma unroll
                for (int nf = 0; nf < 4; ++nf)
                    acc[2 * p + i][nf] = MFMA16(af[i], bf[nf], acc[2 * p + i][nf]);
            __builtin_amdgcn_s_setprio(0);
        }
    }

    int wrow = row0 + wm * 128;
    #pragma unroll
    for (int mf = 0; mf < 8; ++mf) {
        int grow = wrow + mf * 16 + lg * 4;
        #pragma unroll
        for (int nf = 0; nf < 4; ++nf) {
            int gc = col0 + wn * 64 + nf * 16 + lr;
            if (gc >= N) continue;
            if (ROUTE) {
                int which = gc >> 10, lc = gc & 1023;
                float bias = (which == 0 ? bb0 : which == 1 ? bb1 : bb2)[lc];
                float alpha = (which == 0) ? alpha0 : 1.0f;
                short* op = (which == 0 ? o0 : which == 1 ? o1 : o2);
                #pragma unroll
                for (int q = 0; q < 4; ++q) {
                    int r2 = grow + q;
                    if (r2 < M) op[(long)r2 * 1024 + lc] = f2b((acc[mf][nf][q] + bias) * alpha);
                }
            } else {
                float bias = bb0[gc];
                #pragma unroll
                for (int q = 0; q < 4; ++q) {
                    int r2 = grow + q;
                    if (r2 < M) Cf[(long)r2 * N + gc] = acc[mf][nf][q] + bias;
                }
            }
        }
    }
}

// ---------------- 128^2 core for att partials ----------------
__device__ __forceinline__ void gemm_core(
    const short* __restrict__ Ab, const short* __restrict__ Bb,
    float* __restrict__ Cf, int M, int N, int K, int ldc, int row0, int col0) {
    __shared__ short As[128 * 64];
    __shared__ short Bs[128 * 64];
    int tid = threadIdx.x;
    int lane = tid & 63, wave = tid >> 6;
    int wr = wave >> 1, wc = wave & 1;
    int lr = lane & 15, lg = lane >> 4;
    f32x4 acc[4][4];
    #pragma unroll
    for (int i = 0; i < 4; i++)
        #pragma unroll
        for (int j = 0; j < 4; j++)
            #pragma unroll
            for (int q = 0; q < 4; q++) acc[i][j][q] = 0.f;

    for (int k0 = 0; k0 < K; k0 += 64) {
        __syncthreads();
        #pragma unroll
        for (int i = 0; i < 4; ++i) {
            int cw = i * 256 + wave * 64;
            int c = cw + lane;
            int r = c >> 3;
            int cs = (c & 7) * 8;
            int ra = row0 + r; ra = ra < M ? ra : M - 1;
            gload16(Ab + (long)ra * K + k0 + cs, &As[cw * 8]);
            int rb = col0 + r; rb = rb < N ? rb : N - 1;
            gload16(Bb + (long)rb * K + k0 + cs, &Bs[cw * 8]);
        }
        __syncthreads();
        #pragma unroll
        for (int ks = 0; ks < 2; ++ks) {
            s16x8 af[4], bfr[4];
            #pragma unroll
            for (int i = 0; i < 4; ++i)
                af[i] = *(const s16x8*)&As[(wr * 64 + i * 16 + lr) * 64 + ks * 32 + lg * 8];
            #pragma unroll
            for (int j = 0; j < 4; ++j)
                bfr[j] = *(const s16x8*)&Bs[(wc * 64 + j * 16 + lr) * 64 + ks * 32 + lg * 8];
            #pragma unroll
            for (int i = 0; i < 4; ++i)
                #pragma unroll
                for (int j = 0; j < 4; ++j)
                    acc[i][j] = MFMA16(af[i], bfr[j], acc[i][j]);
        }
    }
    #pragma unroll
    for (int i = 0; i < 4; i++) {
        int rbase = row0 + wr * 64 + i * 16 + lg * 4;
        #pragma unroll
        for (int j = 0; j < 4; j++) {
            int c = col0 + wc * 64 + j * 16 + lr;
            if (c >= N) continue;
            #pragma unroll
            for (int q = 0; q < 4; q++) {
                int r = rbase + q;
                if (r >= M) continue;
                Cf[(long)r * ldc + c] = acc[i][j][q];
            }
        }
    }
}

__global__ __launch_bounds__(256) void k_att(
    const short* __restrict__ q, const short* __restrict__ k,
    float* __restrict__ attp, int T, int E) {
    int z = blockIdx.z;
    gemm_core(q + (long)z * T * E, k + (long)z * T * E,
              attp + (long)z * T * T, T, T, E, T,
              blockIdx.y * 128, blockIdx.x * 128);
}

// ---------------- mean over heads of K ----------------
__global__ void k_mean_keys8(const short* __restrict__ Kb, float* __restrict__ out, int BT) {
    int i = blockIdx.x * blockDim.x + threadIdx.x;
    if (i >= BT * 8) return;
    int bt = i >> 3, d0 = (i & 7) * 8;
    const short* p = Kb + (long)bt * 1024 + d0;
    float s[8] = {0.f, 0.f, 0.f, 0.f, 0.f, 0.f, 0.f, 0.f};
    #pragma unroll
    for (int h = 0; h < 16; ++h) {
        s16x8 v = *(const s16x8*)(p + h * 64);
        #pragma unroll
        for (int j = 0; j < 8; ++j) s[j] += b2f(v[j]);
    }
    float4 o0 = {s[0] * 0.0625f, s[1] * 0.0625f, s[2] * 0.0625f, s[3] * 0.0625f};
    float4 o1 = {s[4] * 0.0625f, s[5] * 0.0625f, s[6] * 0.0625f, s[7] * 0.0625f};
    *(float4*)(out + (long)bt * 64 + d0) = o0;
    *(float4*)(out + (long)bt * 64 + d0 + 4) = o1;
}

// ---------------- reduce att_score partials over batch ----------------
// scale = ln2/256 compensates the log2e folded into q
__global__ void k_att_reduce(const float* __restrict__ part, float* __restrict__ out,
                             int n, int nb, long stride) {
    int i = blockIdx.x * blockDim.x + threadIdx.x;
    if (i >= n) return;
    float s = 0.f;
    for (int b = 0; b < nb; ++b) s += part[(long)b * stride + i];
    out[i] = s * 0.002707606174062286f;  // ln(2)/256
}

// ---------------- V transpose: v[B,T,H*64] -> vt[B*H][64][TP] ----------------
__global__ __launch_bounds__(256) void k_vtrans(const short* __restrict__ v, short* __restrict__ vt,
                                                int B, int T, int H, int TP) {
    int b = blockIdx.z, h = blockIdx.y, t0 = blockIdx.x * 64;
    __shared__ short Vs[64][68];
    int tid = threadIdx.x;
    for (int c = tid; c < 512; c += 256) {
        int r = c >> 3, m = c & 7;
        s16x8 val = {0,0,0,0,0,0,0,0};
        if (t0 + r < T) val = *(const s16x8*)(v + ((long)(b * T + t0 + r)) * (H * 64) + h * 64 + m * 8);
        *(s16x8*)&Vs[r][m * 8] = val;
    }
    __syncthreads();
    for (int c = tid; c < 512; c += 256) {
        int d = c >> 3, mw = c & 7;
        s16x8 o;
        #pragma unroll
        for (int j = 0; j < 8; j++) o[j] = Vs[mw * 8 + j][d];
        *(s16x8*)(vt + ((long)((b * H + h) * 64 + d)) * TP + t0 + mw * 8) = o;
    }
}

// ---------------- flash attention v4: size-weighted exp2 softmax, per-lane lsum ----------------
__global__ __launch_bounds__(256) void k_flash(
    const short* __restrict__ Q, const short* __restrict__ Kb, const short* __restrict__ VT,
    const float* __restrict__ szp, short* __restrict__ Ctx,
    int B, int T, int E, int H, int SP, int TP, int NTQ) {
    int nwg = gridDim.x;
    int cpx = nwg >> 3;
    int wg = (blockIdx.x & 7) * cpx + (blockIdx.x >> 3);
    int tq = wg % NTQ, h = (wg / NTQ) % H, b = wg / (NTQ * H);
    int t0 = tq * 128;

    __shared__ short Ks[64][68];
    __shared__ short Vt[64][68];
    __shared__ short Ps[4][32][68];
    __shared__ float Ls[64];
    int tid = threadIdx.x, wid = tid >> 6, lane = tid & 63;
    int lr = lane & 15, lg = lane >> 4;

    s16x8 aqf[2][2];
    #pragma unroll
    for (int i = 0; i < 2; ++i) {
        int t = t0 + wid * 32 + i * 16 + lr; t = t < T ? t : T - 1;
        #pragma unroll
        for (int ks = 0; ks < 2; ++ks)
            aqf[i][ks] = *(const s16x8*)(Q + ((long)b * T + t) * E + h * 64 + ks * 32 + lg * 8);
    }

    const short* kb  = Kb + (long)b * T * E + h * 64;
    const short* vtb = VT + ((long)(b * H + h)) * 64 * TP;

    int c0 = tid, c1 = tid + 256;
    int r0 = c0 >> 3, m0 = c0 & 7, r1 = c1 >> 3, m1 = c1 & 7;
    s16x8 kreg0, kreg1, vreg0, vreg1;
    float lreg = 0.f;

    {
        int s = r0; s = s < T ? s : T - 1;
        kreg0 = *(const s16x8*)(kb + (long)s * E + m0 * 8);
        s = r1; s = s < T ? s : T - 1;
        kreg1 = *(const s16x8*)(kb + (long)s * E + m1 * 8);
        vreg0 = *(const s16x8*)(vtb + (long)r0 * TP + 0 + m0 * 8);
        vreg1 = *(const s16x8*)(vtb + (long)r1 * TP + 0 + m1 * 8);
        if (tid < 64) lreg = szp[b * SP + 0 + tid];
    }

    float mreg[2][4], lsum[2][4];
    f32x4 o[2][4];
    #pragma unroll
    for (int i = 0; i < 2; i++)
        #pragma unroll
        for (int q = 0; q < 4; q++) { mreg[i][q] = -INFINITY; lsum[i][q] = 0.f; }
    #pragma unroll
    for (int i = 0; i < 2; i++)
        #pragma unroll
        for (int jd = 0; jd < 4; jd++)
            #pragma unroll
            for (int q = 0; q < 4; q++) o[i][jd][q] = 0.f;

    for (int s0 = 0; s0 < T; s0 += 64) {
        *(s16x8*)&Ks[r0][m0 * 8] = kreg0;
        *(s16x8*)&Ks[r1][m1 * 8] = kreg1;
        *(s16x8*)&Vt[r0][m0 * 8] = vreg0;
        *(s16x8*)&Vt[r1][m1 * 8] = vreg1;
        if (tid < 64) Ls[tid] = lreg;
        __syncthreads();

        if (s0 + 64 < T) {
            int sn = s0 + 64;
            int s = sn + r0; s = s < T ? s : T - 1;
            kreg0 = *(const s16x8*)(kb + (long)s * E + m0 * 8);
            s = sn + r1; s = s < T ? s : T - 1;
            kreg1 = *(const s16x8*)(kb + (long)s * E + m1 * 8);
            vreg0 = *(const s16x8*)(vtb + (long)r0 * TP + sn + m0 * 8);
            vreg1 = *(const s16x8*)(vtb + (long)r1 * TP + sn + m1 * 8);
            if (tid < 64) lreg = szp[b * SP + sn + tid];
        }

        float szv[4];
        #pragma unroll
        for (int j = 0; j < 4; j++) szv[j] = Ls[j * 16 + lr];

        s16x8 kf[2][4];
        #pragma unroll
        for (int ks = 0; ks < 2; ++ks)
            #pragma unroll
            for (int j = 0; j < 4; ++j)
                kf[ks][j] = *(const s16x8*)&Ks[j * 16 + lr][ks * 32 + lg * 8];

        #pragma unroll
        for (int i = 0; i < 2; ++i) {
            f32x4 sf[4];
            #pragma unroll
            for (int j = 0; j < 4; j++)
                #pragma unroll
                for (int q = 0; q < 4; q++) sf[j][q] = 0.f;
            __builtin_amdgcn_s_setprio(1);
            #pragma unroll
            for (int ks = 0; ks < 2; ++ks)
                #pragma unroll
                for (int j = 0; j < 4; j++) sf[j] = MFMA16(aqf[i][ks], kf[ks][j], sf[j]);
            __builtin_amdgcn_s_setprio(0);

            float tmax[4];
            #pragma unroll
            for (int q = 0; q < 4; q++)
                tmax[q] = fmaxf(fmaxf(sf[0][q], sf[1][q]), fmaxf(sf[2][q], sf[3][q]));
            int ok = 1;
            #pragma unroll
            for (int q = 0; q < 4; q++) ok &= (tmax[q] <= mreg[i][q] + 11.0f) ? 1 : 0;
            if (!__all(ok)) {
                #pragma unroll
                for (int q = 0; q < 4; q++) {
                    #pragma unroll
                    for (int msk = 1; msk < 16; msk <<= 1)
                        tmax[q] = fmaxf(tmax[q], __shfl_xor(tmax[q], msk));
                    float mn = fmaxf(mreg[i][q], tmax[q]);
                    float al = exp2f(mreg[i][q] - mn);
                    mreg[i][q] = mn;
                    lsum[i][q] *= al;
                    #pragma unroll
                    for (int jd = 0; jd < 4; jd++) o[i][jd][q] *= al;
                }
            }
            float rs[4] = {0.f, 0.f, 0.f, 0.f};
            #pragma unroll
            for (int j = 0; j < 4; j++) {
                float szj = szv[j];
                #pragma unroll
                for (int q = 0; q < 4; q++) {
                    float p = exp2f(sf[j][q] - mreg[i][q]) * szj;
                    sf[j][q] = p;
                    rs[q] += p;
                }
            }
            #pragma unroll
            for (int q = 0; q < 4; q++) lsum[i][q] += rs[q];

            #pragma unroll
            for (int j = 0; j < 4; j++)
                #pragma unroll
                for (int q = 0; q < 4; q++)
                    Ps[wid][i * 16 + lg * 4 + q][j * 16 + lr] = f2b(sf[j][q]);

            __builtin_amdgcn_s_setprio(1);
            #pragma unroll
            for (int ks = 0; ks < 2; ++ks) {
                s16x8 ap = *(const s16x8*)&Ps[wid][i * 16 + lr][ks * 32 + lg * 8];
                #pragma unroll
                for (int jd = 0; jd < 4; jd++) {
                    s16x8 bv = *(const s16x8*)&Vt[jd * 16 + lr][ks * 32 + lg * 8];
                    o[i][jd] = MFMA16(ap, bv, o[i][jd]);
                }
            }
            __builtin_amdgcn_s_setprio(0);
        }
        __syncthreads();
    }

    short* cb = Ctx + ((long)b * T + t0) * E + h * 64;
    #pragma unroll
    for (int i = 0; i < 2; i++)
        #pragma unroll
        for (int q = 0; q < 4; q++) {
            float s = lsum[i][q];
            s += __shfl_xor(s, 1); s += __shfl_xor(s, 2);
            s += __shfl_xor(s, 4); s += __shfl_xor(s, 8);
            int t = wid * 32 + i * 16 + lg * 4 + q;
            if (t0 + t >= T) continue;
            float inv = 1.f / s;
            #pragma unroll
            for (int jd = 0; jd < 4; jd++)
                cb[(long)t * E + jd * 16 + lr] = f2b(o[i][jd][q] * inv);
        }
}

extern "C" void kernel_launch(void* const* d_in, const int* in_sizes, int n_in,
                              void* d_out, int out_size, void* d_ws, size_t ws_size,
                              hipStream_t stream) {
    (void)in_sizes; (void)n_in; (void)out_size; (void)ws_size;
    const int B = 16, T = 577, E = 1024, H = 16;
    const int SP = 640, TP = 640;
    const float* hs   = (const float*)d_in[0];
    const float* size = (const float*)d_in[1];
    const float* wq   = (const float*)d_in[2];
    const float* bq   = (const float*)d_in[3];
    const float* wk   = (const float*)d_in[4];
    const float* bk   = (const float*)d_in[5];
    const float* wv   = (const float*)d_in[6];
    const float* bv   = (const float*)d_in[7];
    const float* wo   = (const float*)d_in[8];
    const float* bo   = (const float*)d_in[9];

    float* out_attn = (float*)d_out;                  // B*T*E
    float* out_mk   = out_attn + (long)B * T * E;     // B*T*D
    float* out_as   = out_mk + (long)B * T * 64;      // T*T

    long nBTE = (long)B * T * E;
    long nEE  = (long)E * E;
    char* ws = (char*)d_ws;
    short* hs_b  = (short*)ws; ws += nBTE * 2;
    short* wq_b  = (short*)ws; ws += nEE * 2;   // wq|wk|wv contiguous -> [3072][1024]
    short* wk_b  = (short*)ws; ws += nEE * 2;
    short* wv_b  = (short*)ws; ws += nEE * 2;
    short* wo_b  = (short*)ws; ws += nEE * 2;
    short* q_b   = (short*)ws; ws += nBTE * 2;
    short* k_b   = (short*)ws; ws += nBTE * 2;
    short* v_b   = (short*)ws; ws += nBTE * 2;
    short* ctx_b = (short*)ws; ws += nBTE * 2;
    float* szpad = (float*)ws; ws += (long)B * SP * 4;
    float* att_p = (float*)ws; ws += (long)B * T * T * 4;
    short* vt = (short*)att_p;   // aliases att_p, written after reduce consumed it

    k_f32_to_bf16<<<2048, 256, 0, stream>>>(hs, hs_b, nBTE);
    k_f32_to_bf16<<<1024, 256, 0, stream>>>(wq, wq_b, nEE);
    k_f32_to_bf16<<<1024, 256, 0, stream>>>(wk, wk_b, nEE);
    k_f32_to_bf16<<<1024, 256, 0, stream>>>(wv, wv_b, nEE);
    k_f32_to_bf16<<<1024, 256, 0, stream>>>(wo, wo_b, nEE);
    k_sizepad<<<(B * SP + 255) / 256, 256, 0, stream>>>(size, szpad, B, T, SP);

    int M = B * T;  // 9232
    // fused QKV; q carries 0.125*log2(e) for exp2-domain softmax (compensated in att_reduce)
    {
        int Mtiles = (M + 255) / 256, Ntiles = 3072 / 256;
        k_gemm8<true><<<Mtiles * Ntiles, 512, 0, stream>>>(
            hs_b, wq_b, bq, bk, bv, q_b, k_b, v_b, nullptr, M, 3072, E, Ntiles,
            0.18033688011112042f);  // 0.125 * log2(e)
    }

    dim3 g_att((T + 127) / 128, (T + 127) / 128, B);
    k_att<<<g_att, dim3(256), 0, stream>>>(q_b, k_b, att_p, T, E);
    k_att_reduce<<<((T * T) + 255) / 256, 256, 0, stream>>>(att_p, out_as, T * T, B, (long)T * T);

    dim3 g_vt((T + 63) / 64, H, B);
    k_vtrans<<<g_vt, dim3(256), 0, stream>>>(v_b, vt, B, T, H, TP);

    k_mean_keys8<<<((B * T * 8) + 255) / 256, 256, 0, stream>>>(k_b, out_mk, B * T);

    const int NTQ = (T + 127) / 128;
    int nfl = NTQ * H * B;
    k_flash<<<nfl, dim3(256), 0, stream>>>(q_b, k_b, vt, szpad, ctx_b, B, T, E, H, SP, TP, NTQ);

    {
        int Mtiles = (M + 255) / 256, Ntiles = 1024 / 256;
        k_gemm8<false><<<Mtiles * Ntiles, 512, 0, stream>>>(
            ctx_b, wo_b, bo, nullptr, nullptr, nullptr, nullptr, nullptr,
            out_attn, M, 1024, E, Ntiles, 1.0f);
    }
}